// Round 2
// baseline (1074.342 us; speedup 1.0000x reference)
//
#include <hip/hip_runtime.h>
#include <math.h>

#define N_PART 4096
#define N_T    400
#define N_O    9
#define CH     8            // timesteps per output chunk
#define NCH    (N_T/CH)     // 50 chunks, exact
#define YPC    (CH*N_O)     // 72 ypred floats per particle per chunk
#define YSTR   73           // odd stride -> conflict-free LDS
#define PSTR   17
#define LOG2PI_F 1.8378770664093453f

__device__ __forceinline__ float frcp(float x) { return __builtin_amdgcn_rcpf(x); }

// One thread per particle; block = 1 wave (64). All matrix work in registers.
// Regime 1: Woodbury with diagonal G (disjoint L1 column supports).
// Regime 2: Sherman-Morrison rank-1.
// Outputs staged in LDS and flushed coalesced every CH steps (the round-1
// bottleneck was 11 scattered global stores/step: 64 cache lines per instr).
__global__ __launch_bounds__(64)
void imm_kf_kernel(const float* __restrict__ y,
                   const float* __restrict__ B1s1,
                   const float* __restrict__ B1s2,
                   const float* __restrict__ l1f,
                   const float* __restrict__ l2f,
                   const float* __restrict__ log_q,
                   const float* __restrict__ log_r,
                   const float* __restrict__ gip,
                   const float* __restrict__ gcp,
                   float* __restrict__ out_probs,   // [N,NT,2]
                   float* __restrict__ out_ypred,   // [N,NT,9]
                   float* __restrict__ ll_ws)
{
    __shared__ float syp[64][YSTR];   // ypred staging: [particle][CH*9]
    __shared__ float spb[64][PSTR];   // probs staging: [particle][CH*2]

    const int lane = threadIdx.x;
    const int n = blockIdx.x * 64 + lane;

    // ---- uniform constants ----
    float B1[3][3];
#pragma unroll
    for (int i = 0; i < 3; ++i)
#pragma unroll
        for (int j = 0; j < 3; ++j) B1[i][j] = B1s1[i*3+j];
    const float b2 = B1s2[0];

    float lam1[9], lam2[9];
    lam1[0] = 1.0f; lam1[1] = l1f[0]; lam1[2] = l1f[1];
    lam1[3] = 1.0f; lam1[4] = l1f[2]; lam1[5] = l1f[3];
    lam1[6] = 1.0f; lam1[7] = l1f[4]; lam1[8] = l1f[5];
    lam2[0] = 1.0f;
#pragma unroll
    for (int o = 1; o < 9; ++o) lam2[o] = l2f[o-1];

    float q[4];
#pragma unroll
    for (int i = 0; i < 4; ++i) q[i] = expf(log_q[i]);

    float ri[9], a1[9], u2[9];
    float logdetR = 0.0f;
    float g[3] = {0.f,0.f,0.f}, gh[3] = {0.f,0.f,0.f};
    float g2 = 0.0f, gh2 = 0.0f;
#pragma unroll
    for (int o = 0; o < 9; ++o) {
        float rr  = expf(log_r[o]);
        float rj  = rr + 1e-6f;           // R + JITTER folded
        float riv = 1.0f / rj;
        ri[o] = riv;
        logdetR += logf(rj);
        a1[o] = lam1[o] * riv;
        u2[o] = lam2[o] * riv;
        const int c = o / 3;
        g[c]  += lam1[o] * a1[o];
        gh[c] += a1[o] * a1[o] * rr;
        g2  += lam2[o] * u2[o];
        gh2 += u2[o] * u2[o] * rr;
    }
    const float gi  = gip[0];
    const float gc0 = gcp[0], gc1 = gcp[1], gc2 = gcp[2];
    const float llconst = 9.0f * LOG2PI_F + logdetR;

    // ---- state ----
    float P[4][4];
#pragma unroll
    for (int i = 0; i < 4; ++i)
#pragma unroll
        for (int j = 0; j < 4; ++j) P[i][j] = (i == j) ? 1000.0f : 0.0f;
    float eta[4] = {0.f,0.f,0.f,0.f};
    float pr1 = 0.99f, pr2 = 0.01f;
    float llacc = 0.0f;

    const float* yb = y + (size_t)n * (N_T * N_O);

    float ycur[9];
#pragma unroll
    for (int o = 0; o < 9; ++o) ycur[o] = yb[o];

    for (int c = 0; c < NCH; ++c) {
#pragma unroll
        for (int tt = 0; tt < CH; ++tt) {
            const int t = c*CH + tt;
            // prefetch next timestep's observations (latency hiding)
            float ynx[9];
            const int tn = (t + 1 < N_T) ? (t + 1) : t;
            const float* ybn = yb + tn * N_O;
#pragma unroll
            for (int o = 0; o < 9; ++o) ynx[o] = ybn[o];

            const float xg  = gi + eta[0]*gc0 + eta[1]*gc1 + eta[2]*gc2;
            const float p11 = frcp(1.0f + __expf(-xg));

            // ---- prediction ----
            float ep[4];
#pragma unroll
            for (int i = 0; i < 3; ++i)
                ep[i] = B1[i][0]*eta[0] + B1[i][1]*eta[1] + B1[i][2]*eta[2];
            ep[3] = b2 * eta[3];

            float C[3][3];
#pragma unroll
            for (int i = 0; i < 3; ++i)
#pragma unroll
                for (int k = 0; k < 3; ++k)
                    C[i][k] = B1[i][0]*P[0][k] + B1[i][1]*P[1][k] + B1[i][2]*P[2][k];

            float Pp[4][4];
#pragma unroll
            for (int i = 0; i < 3; ++i)
#pragma unroll
                for (int j = i; j < 3; ++j) {
                    float s = C[i][0]*B1[j][0] + C[i][1]*B1[j][1] + C[i][2]*B1[j][2];
                    if (i == j) s += q[i];
                    Pp[i][j] = s; Pp[j][i] = s;
                }
#pragma unroll
            for (int i = 0; i < 3; ++i) {
                float s = b2 * (B1[i][0]*P[0][3] + B1[i][1]*P[1][3] + B1[i][2]*P[2][3]);
                Pp[i][3] = s; Pp[3][i] = s;
            }
            Pp[3][3] = b2*b2*P[3][3] + q[3];

            // ---- regime 1 (Woodbury, diagonal G) ----
            float v1[9];
#pragma unroll
            for (int o = 0; o < 9; ++o) v1[o] = ycur[o] - lam1[o]*ep[o/3];
            float vRv1 = 0.0f;
#pragma unroll
            for (int o = 0; o < 9; ++o) vRv1 += v1[o]*v1[o]*ri[o];
            const float b0  = a1[0]*v1[0] + a1[1]*v1[1] + a1[2]*v1[2];
            const float b1  = a1[3]*v1[3] + a1[4]*v1[4] + a1[5]*v1[5];
            const float bb2 = a1[6]*v1[6] + a1[7]*v1[7] + a1[8]*v1[8];

            const float M00 = 1.0f + Pp[0][0]*g[0], M01 = Pp[0][1]*g[1], M02 = Pp[0][2]*g[2];
            const float M10 = Pp[1][0]*g[0], M11 = 1.0f + Pp[1][1]*g[1], M12 = Pp[1][2]*g[2];
            const float M20 = Pp[2][0]*g[0], M21 = Pp[2][1]*g[1], M22 = 1.0f + Pp[2][2]*g[2];

            const float co00 = M11*M22 - M12*M21;
            const float co01 = M12*M20 - M10*M22;
            const float co02 = M10*M21 - M11*M20;
            const float det  = M00*co00 + M01*co01 + M02*co02;   // > 1 (S,G PD)
            const float idet = frcp(det);
            const float Mi00 = co00*idet;
            const float Mi01 = (M02*M21 - M01*M22)*idet;
            const float Mi02 = (M01*M12 - M02*M11)*idet;
            const float Mi10 = co01*idet;
            const float Mi11 = (M00*M22 - M02*M20)*idet;
            const float Mi12 = (M02*M10 - M00*M12)*idet;
            const float Mi20 = co02*idet;
            const float Mi21 = (M01*M20 - M00*M21)*idet;
            const float Mi22 = (M00*M11 - M01*M10)*idet;

            const float sb0 = Pp[0][0]*b0 + Pp[0][1]*b1 + Pp[0][2]*bb2;
            const float sb1 = Pp[1][0]*b0 + Pp[1][1]*b1 + Pp[1][2]*bb2;
            const float sb2 = Pp[2][0]*b0 + Pp[2][1]*b1 + Pp[2][2]*bb2;
            const float ms0 = Mi00*sb0 + Mi01*sb1 + Mi02*sb2;
            const float ms1 = Mi10*sb0 + Mi11*sb1 + Mi12*sb2;
            const float ms2 = Mi20*sb0 + Mi21*sb1 + Mi22*sb2;
            const float qf1 = vRv1 - (b0*ms0 + b1*ms1 + bb2*ms2);
            const float ll1 = -0.5f*(llconst + __logf(det) + qf1);

            float J[4][3];
#pragma unroll
            for (int l = 0; l < 4; ++l) {
                J[l][0] = Pp[l][0]*Mi00 + Pp[l][1]*Mi01 + Pp[l][2]*Mi02;
                J[l][1] = Pp[l][0]*Mi10 + Pp[l][1]*Mi11 + Pp[l][2]*Mi12;
                J[l][2] = Pp[l][0]*Mi20 + Pp[l][1]*Mi21 + Pp[l][2]*Mi22;
            }
            float eta1[4];
#pragma unroll
            for (int l = 0; l < 4; ++l)
                eta1[l] = ep[l] + J[l][0]*b0 + J[l][1]*b1 + J[l][2]*bb2;

            float Jg[4][3];
#pragma unroll
            for (int l = 0; l < 4; ++l) {
                Jg[l][0] = J[l][0]*g[0];
                Jg[l][1] = J[l][1]*g[1];
                Jg[l][2] = J[l][2]*g[2];
            }
            float Z[4][4];
#pragma unroll
            for (int i = 0; i < 4; ++i)
#pragma unroll
                for (int j = 0; j < 4; ++j)
                    Z[i][j] = Jg[i][0]*Pp[j][0] + Jg[i][1]*Pp[j][1] + Jg[i][2]*Pp[j][2];

            float P1[4][4];
#pragma unroll
            for (int i = 0; i < 4; ++i)
#pragma unroll
                for (int j = i; j < 4; ++j) {
                    const float w  = Z[i][0]*Jg[j][0] + Z[i][1]*Jg[j][1] + Z[i][2]*Jg[j][2];
                    const float yv = J[i][0]*gh[0]*J[j][0] + J[i][1]*gh[1]*J[j][1] + J[i][2]*gh[2]*J[j][2];
                    const float val = Pp[i][j] - Z[i][j] - Z[j][i] + w + yv;
                    P1[i][j] = val; P1[j][i] = val;
                }

            // ---- regime 2 (rank-1) ----
            float v2[9];
#pragma unroll
            for (int o = 0; o < 9; ++o) v2[o] = ycur[o] - lam2[o]*ep[3];
            float vRv2 = 0.0f, bv2 = 0.0f;
#pragma unroll
            for (int o = 0; o < 9; ++o) { vRv2 += v2[o]*v2[o]*ri[o]; bv2 += u2[o]*v2[o]; }
            const float s22 = Pp[3][3];
            const float d2  = 1.0f + s22*g2;
            const float id2 = frcp(d2);
            const float qf2 = vRv2 - s22*id2*bv2*bv2;
            const float ll2 = -0.5f*(llconst + __logf(d2) + qf2);
            const float kv  = bv2 * id2;
            const float p3v[4] = {Pp[0][3], Pp[1][3], Pp[2][3], Pp[3][3]};
            float eta2[4];
#pragma unroll
            for (int l = 0; l < 4; ++l) eta2[l] = ep[l] + p3v[l]*kv;
            const float aa   = g2*id2;
            const float beta = 2.0f*aa - aa*aa*s22 - gh2*id2*id2;
            float P2[4][4];
#pragma unroll
            for (int i = 0; i < 4; ++i)
#pragma unroll
                for (int j = i; j < 4; ++j) {
                    const float val = Pp[i][j] - beta*p3v[i]*p3v[j];
                    P2[i][j] = val; P2[j][i] = val;
                }

            // ---- IMM mixing ----
            const float e1 = __expf(ll1), e2 = __expf(ll2);
            const float num1 = e1 * (pr1 * p11);
            const float num2 = e2 * (pr1 * (1.0f - p11) + pr2);
            const float marg = num1 + num2 + 1e-9f;
            const float im   = frcp(marg);
            const float w1   = num1 * im;
            const float w2m  = num2 * im;
            llacc += __logf(marg);

            float etat[4];
#pragma unroll
            for (int l = 0; l < 4; ++l) etat[l] = w1*eta1[l] + w2m*eta2[l];
#pragma unroll
            for (int i = 0; i < 4; ++i)
#pragma unroll
                for (int j = i; j < 4; ++j) {
                    const float dd1 = (eta1[i]-etat[i])*(eta1[j]-etat[j]);
                    const float dd2 = (eta2[i]-etat[i])*(eta2[j]-etat[j]);
                    const float val = w1*(P1[i][j]+dd1) + w2m*(P2[i][j]+dd2);
                    P[i][j] = val; P[j][i] = val;
                }
#pragma unroll
            for (int l = 0; l < 4; ++l) eta[l] = etat[l];
            pr1 = w1; pr2 = w2m;

            // ---- stage outputs in LDS (conflict-free: odd strides) ----
            spb[lane][tt*2+0] = w1;
            spb[lane][tt*2+1] = w2m;
#pragma unroll
            for (int o = 0; o < 9; ++o)
                syp[lane][tt*9+o] = w1*lam1[o]*etat[o/3] + w2m*lam2[o]*etat[3];

#pragma unroll
            for (int o = 0; o < 9; ++o) ycur[o] = ynx[o];
        }

        // ---- coalesced flush of this chunk's outputs ----
        __syncthreads();
        const int base = blockIdx.x * 64;
        for (int p = 0; p < 64; ++p) {
            const size_t row = (size_t)(base + p);
            float* gyp = out_ypred + row * (N_T*N_O) + c * YPC;
            gyp[lane] = syp[p][lane];
            if (lane < YPC - 64) gyp[64 + lane] = syp[p][64 + lane];
            if (lane < CH*2) {
                float* gpb = out_probs + row * (N_T*2) + c * (CH*2);
                gpb[lane] = spb[p][lane];
            }
        }
        __syncthreads();
    }

    // ---- wave reduction of ll, one atomic per block ----
#pragma unroll
    for (int off = 32; off > 0; off >>= 1)
        llacc += __shfl_down(llacc, off, 64);
    if (lane == 0) atomicAdd(ll_ws, llacc);
}

__global__ void finalize_kernel(const float* __restrict__ ll_ws, float* __restrict__ out0)
{
    out0[0] = -ll_ws[0];
}

extern "C" void kernel_launch(void* const* d_in, const int* in_sizes, int n_in,
                              void* d_out, int out_size, void* d_ws, size_t ws_size,
                              hipStream_t stream)
{
    const float* y    = (const float*)d_in[0];
    const float* B1s1 = (const float*)d_in[1];
    const float* B1s2 = (const float*)d_in[2];
    const float* l1f  = (const float*)d_in[3];
    const float* l2f  = (const float*)d_in[4];
    const float* lq   = (const float*)d_in[5];
    const float* lr   = (const float*)d_in[6];
    const float* gi   = (const float*)d_in[7];
    const float* gc   = (const float*)d_in[8];

    float* out   = (float*)d_out;
    float* probs = out + 1;                                    // [N,NT,2]
    float* ypred = out + 1 + (size_t)N_PART * N_T * 2;         // [N,NT,9]
    float* ws    = (float*)d_ws;

    hipMemsetAsync(ws, 0, sizeof(float), stream);
    imm_kf_kernel<<<N_PART/64, 64, 0, stream>>>(y, B1s1, B1s2, l1f, l2f,
                                                lq, lr, gi, gc, probs, ypred, ws);
    finalize_kernel<<<1, 1, 0, stream>>>(ws, out);
}

// Round 3
// 573.926 us; speedup vs baseline: 1.8719x; 1.8719x over previous
//
#include <hip/hip_runtime.h>
#include <math.h>

#define N_PART 4096
#define N_T    400
#define N_O    9
#define LOG2PI_F 1.8378770664093453f

__device__ __forceinline__ float frcp(float x) { return __builtin_amdgcn_rcpf(x); }

// One thread per particle; block = 1 wave. VALU-issue-bound (round-1 evidence:
// 82% issue on active SIMDs) -> minimize dynamic instruction count.
// Regime 1: Woodbury, diagonal G, SIMPLE covariance form P1 = Pp - Jg*Pc^T
//           with symmetric W = (I+GS)^-1 G  (Joseph form dropped: identical in
//           exact arithmetic, diff is the 1e-6 jitter term only).
// Regime 2: Sherman-Morrison rank-1, simple form beta = g2/d2.
__global__ __launch_bounds__(64)
void imm_kf_kernel(const float* __restrict__ y,
                   const float* __restrict__ B1s1,
                   const float* __restrict__ B1s2,
                   const float* __restrict__ l1f,
                   const float* __restrict__ l2f,
                   const float* __restrict__ log_q,
                   const float* __restrict__ log_r,
                   const float* __restrict__ gip,
                   const float* __restrict__ gcp,
                   float* __restrict__ out_probs,   // [N,NT,2]
                   float* __restrict__ out_ypred,   // [N,NT,9]
                   float* __restrict__ ll_ws)
{
    const int n = blockIdx.x * 64 + threadIdx.x;

    // ---- uniform constants ----
    float B1[3][3];
#pragma unroll
    for (int i = 0; i < 3; ++i)
#pragma unroll
        for (int j = 0; j < 3; ++j) B1[i][j] = B1s1[i*3+j];
    const float b2 = B1s2[0];

    float lam1[9], lam2[9];
    lam1[0] = 1.0f; lam1[1] = l1f[0]; lam1[2] = l1f[1];
    lam1[3] = 1.0f; lam1[4] = l1f[2]; lam1[5] = l1f[3];
    lam1[6] = 1.0f; lam1[7] = l1f[4]; lam1[8] = l1f[5];
    lam2[0] = 1.0f;
#pragma unroll
    for (int o = 1; o < 9; ++o) lam2[o] = l2f[o-1];

    float q[4];
#pragma unroll
    for (int i = 0; i < 4; ++i) q[i] = expf(log_q[i]);

    float ri[9], aA[9], cB[9];
    float logdetR = 0.0f;
    float gA0 = 0.f, gA1 = 0.f, gA2 = 0.f;   // diag of G = U^T R~^-1 U (regime 1)
    float gB = 0.0f;                          // lam2^T R~^-1 lam2 (regime 2)
#pragma unroll
    for (int o = 0; o < 9; ++o) {
        const float rr  = expf(log_r[o]);
        const float rj  = rr + 1e-6f;         // R + JITTER folded
        const float riv = 1.0f / rj;
        ri[o] = riv;
        logdetR += logf(rj);
        aA[o] = lam1[o] * riv;
        cB[o] = lam2[o] * riv;
        const float ga = lam1[o] * aA[o];
        if (o < 3) gA0 += ga; else if (o < 6) gA1 += ga; else gA2 += ga;
        gB += lam2[o] * cB[o];
    }
    const float gi  = gip[0];
    const float gc0 = gcp[0], gc1 = gcp[1], gc2 = gcp[2];
    const float llconst = 9.0f * LOG2PI_F + logdetR;

    // ---- state ----
    float P[4][4];
#pragma unroll
    for (int i = 0; i < 4; ++i)
#pragma unroll
        for (int j = 0; j < 4; ++j) P[i][j] = (i == j) ? 1000.0f : 0.0f;
    float eta[4] = {0.f,0.f,0.f,0.f};
    float pr1 = 0.99f, pr2 = 0.01f;
    float llacc = 0.0f;

    const float* yb = y + (size_t)n * (N_T * N_O);
    float* pb = out_probs + (size_t)n * (N_T * 2);
    float* yp = out_ypred + (size_t)n * (N_T * N_O);

    float ycur[9];
#pragma unroll
    for (int o = 0; o < 9; ++o) ycur[o] = yb[o];
    const float* ynp = yb + N_O;              // points at row min(t+1, 399)

    for (int t = 0; t < N_T; ++t) {
        // prefetch next timestep's observations (covers HBM latency)
        float ynx[9];
#pragma unroll
        for (int o = 0; o < 9; ++o) ynx[o] = ynp[o];
        if (t < N_T - 2) ynp += N_O;

        const float xg  = gi + eta[0]*gc0 + eta[1]*gc1 + eta[2]*gc2;
        const float p11 = frcp(1.0f + __expf(-xg));

        // ---- prediction: ep = B eta ; Pp = B P B^T + Q ----
        float ep[4];
#pragma unroll
        for (int i = 0; i < 3; ++i)
            ep[i] = B1[i][0]*eta[0] + B1[i][1]*eta[1] + B1[i][2]*eta[2];
        ep[3] = b2 * eta[3];

        float C[3][3];
#pragma unroll
        for (int i = 0; i < 3; ++i)
#pragma unroll
            for (int k = 0; k < 3; ++k)
                C[i][k] = B1[i][0]*P[0][k] + B1[i][1]*P[1][k] + B1[i][2]*P[2][k];

        float Pp[4][4];
#pragma unroll
        for (int i = 0; i < 3; ++i)
#pragma unroll
            for (int j = i; j < 3; ++j) {
                float s = C[i][0]*B1[j][0] + C[i][1]*B1[j][1] + C[i][2]*B1[j][2];
                if (i == j) s += q[i];
                Pp[i][j] = s; Pp[j][i] = s;
            }
#pragma unroll
        for (int i = 0; i < 3; ++i) {
            float s = b2 * (B1[i][0]*P[0][3] + B1[i][1]*P[1][3] + B1[i][2]*P[2][3]);
            Pp[i][3] = s; Pp[3][i] = s;
        }
        Pp[3][3] = b2*b2*P[3][3] + q[3];

        // ---- regime 1 ----
        float v1[9];
#pragma unroll
        for (int o = 0; o < 9; ++o) v1[o] = ycur[o] - lam1[o]*ep[o/3];
        float vRv1 = 0.0f;
#pragma unroll
        for (int o = 0; o < 9; ++o) vRv1 += v1[o]*v1[o]*ri[o];
        const float b0  = aA[0]*v1[0] + aA[1]*v1[1] + aA[2]*v1[2];
        const float b1  = aA[3]*v1[3] + aA[4]*v1[4] + aA[5]*v1[5];
        const float bb2 = aA[6]*v1[6] + aA[7]*v1[7] + aA[8]*v1[8];

        // A = I + G*S  (S = Pp[0:3][0:3], G = diag(gA))
        const float A00 = 1.0f + gA0*Pp[0][0], A01 = gA0*Pp[0][1], A02 = gA0*Pp[0][2];
        const float A10 = gA1*Pp[0][1], A11 = 1.0f + gA1*Pp[1][1], A12 = gA1*Pp[1][2];
        const float A20 = gA2*Pp[0][2], A21 = gA2*Pp[1][2], A22 = 1.0f + gA2*Pp[2][2];

        const float c00 = A11*A22 - A12*A21;
        const float c01 = A12*A20 - A10*A22;
        const float c02 = A10*A21 - A11*A20;
        const float det = A00*c00 + A01*c01 + A02*c02;      // det(I+GS) > 1
        const float idet = frcp(det);
        // Ainv = adj(A)/det
        const float Ai00 = c00*idet;
        const float Ai01 = (A02*A21 - A01*A22)*idet;
        const float Ai02 = (A01*A12 - A02*A11)*idet;
        const float Ai10 = c01*idet;
        const float Ai11 = (A00*A22 - A02*A20)*idet;
        const float Ai12 = (A02*A10 - A00*A12)*idet;
        const float Ai20 = c02*idet;
        const float Ai21 = (A01*A20 - A00*A21)*idet;
        const float Ai22 = (A00*A11 - A01*A10)*idet;

        // u = A^-1 b   (Minv^T b)
        const float u0 = Ai00*b0 + Ai01*b1 + Ai02*bb2;
        const float u1 = Ai10*b0 + Ai11*b1 + Ai12*bb2;
        const float uu2 = Ai20*b0 + Ai21*b1 + Ai22*bb2;
        // sb = S b
        const float sb0 = Pp[0][0]*b0 + Pp[0][1]*b1 + Pp[0][2]*bb2;
        const float sb1 = Pp[0][1]*b0 + Pp[1][1]*b1 + Pp[1][2]*bb2;
        const float sb2 = Pp[0][2]*b0 + Pp[1][2]*b1 + Pp[2][2]*bb2;
        const float qf1 = vRv1 - (u0*sb0 + u1*sb1 + uu2*sb2);
        const float ll1 = -0.5f*(llconst + __logf(det) + qf1);

        // W = Ainv * G  (symmetric)
        const float W00 = Ai00*gA0, W01 = Ai01*gA1, W02 = Ai02*gA2;
        const float W11 = Ai11*gA1, W12 = Ai12*gA2, W22 = Ai22*gA2;

        float eta1[4];
#pragma unroll
        for (int l = 0; l < 4; ++l)
            eta1[l] = ep[l] + Pp[l<3?l:0][l<3?0:3]*0.0f  // (placeholder removed below)
                    , eta1[l] = ep[l];
#pragma unroll
        for (int l = 0; l < 4; ++l) {
            const float pl0 = (l<1)?Pp[0][0]:((l==1)?Pp[0][1]:((l==2)?Pp[0][2]:Pp[0][3]));
            (void)pl0;
        }
        // rows of Pc = Pp[:, 0:3]; use symmetric storage explicitly
        {
            const float r00=Pp[0][0], r01=Pp[0][1], r02=Pp[0][2];
            const float r10=Pp[0][1], r11=Pp[1][1], r12=Pp[1][2];
            const float r20=Pp[0][2], r21=Pp[1][2], r22=Pp[2][2];
            const float r30=Pp[0][3], r31=Pp[1][3], r32=Pp[2][3];
            eta1[0] = ep[0] + r00*u0 + r01*u1 + r02*uu2;
            eta1[1] = ep[1] + r10*u0 + r11*u1 + r12*uu2;
            eta1[2] = ep[2] + r20*u0 + r21*u1 + r22*uu2;
            eta1[3] = ep[3] + r30*u0 + r31*u1 + r32*uu2;

            // Jg[l][c] = Pc[l] . W[:,c]
            float Jg[4][3];
            Jg[0][0]=r00*W00+r01*W01+r02*W02; Jg[0][1]=r00*W01+r01*W11+r02*W12; Jg[0][2]=r00*W02+r01*W12+r02*W22;
            Jg[1][0]=r10*W00+r11*W01+r12*W02; Jg[1][1]=r10*W01+r11*W11+r12*W12; Jg[1][2]=r10*W02+r11*W12+r12*W22;
            Jg[2][0]=r20*W00+r21*W01+r22*W02; Jg[2][1]=r20*W01+r21*W11+r22*W12; Jg[2][2]=r20*W02+r21*W12+r22*W22;
            Jg[3][0]=r30*W00+r31*W01+r32*W02; Jg[3][1]=r30*W01+r31*W11+r32*W12; Jg[3][2]=r30*W02+r31*W12+r32*W22;

            // P1 = Pp - Jg*Pc^T (upper triangle; symmetric in exact arithmetic)
            float P1[4][4];
            P1[0][0]=Pp[0][0]-(Jg[0][0]*r00+Jg[0][1]*r01+Jg[0][2]*r02);
            P1[0][1]=Pp[0][1]-(Jg[0][0]*r10+Jg[0][1]*r11+Jg[0][2]*r12);
            P1[0][2]=Pp[0][2]-(Jg[0][0]*r20+Jg[0][1]*r21+Jg[0][2]*r22);
            P1[0][3]=Pp[0][3]-(Jg[0][0]*r30+Jg[0][1]*r31+Jg[0][2]*r32);
            P1[1][1]=Pp[1][1]-(Jg[1][0]*r10+Jg[1][1]*r11+Jg[1][2]*r12);
            P1[1][2]=Pp[1][2]-(Jg[1][0]*r20+Jg[1][1]*r21+Jg[1][2]*r22);
            P1[1][3]=Pp[1][3]-(Jg[1][0]*r30+Jg[1][1]*r31+Jg[1][2]*r32);
            P1[2][2]=Pp[2][2]-(Jg[2][0]*r20+Jg[2][1]*r21+Jg[2][2]*r22);
            P1[2][3]=Pp[2][3]-(Jg[2][0]*r30+Jg[2][1]*r31+Jg[2][2]*r32);
            P1[3][3]=Pp[3][3]-(Jg[3][0]*r30+Jg[3][1]*r31+Jg[3][2]*r32);

            // ---- regime 2 (rank-1 Sherman-Morrison, simple form) ----
            float v2[9];
#pragma unroll
            for (int o = 0; o < 9; ++o) v2[o] = ycur[o] - lam2[o]*ep[3];
            float vRv2 = 0.0f, bv2 = 0.0f;
#pragma unroll
            for (int o = 0; o < 9; ++o) { vRv2 += v2[o]*v2[o]*ri[o]; bv2 += cB[o]*v2[o]; }
            const float s22 = Pp[3][3];
            const float d2  = 1.0f + s22*gB;
            const float id2 = frcp(d2);
            const float qf2 = vRv2 - s22*id2*bv2*bv2;
            const float ll2 = -0.5f*(llconst + __logf(d2) + qf2);
            const float kv  = bv2 * id2;
            const float p30=Pp[0][3], p31=Pp[1][3], p32=Pp[2][3], p33=Pp[3][3];
            float eta2[4];
            eta2[0]=ep[0]+p30*kv; eta2[1]=ep[1]+p31*kv;
            eta2[2]=ep[2]+p32*kv; eta2[3]=ep[3]+p33*kv;
            const float beta = gB*id2;
            const float bp0=beta*p30, bp1=beta*p31, bp2=beta*p32, bp3=beta*p33;
            float P2[4][4];
            P2[0][0]=Pp[0][0]-bp0*p30; P2[0][1]=Pp[0][1]-bp0*p31;
            P2[0][2]=Pp[0][2]-bp0*p32; P2[0][3]=Pp[0][3]-bp0*p33;
            P2[1][1]=Pp[1][1]-bp1*p31; P2[1][2]=Pp[1][2]-bp1*p32;
            P2[1][3]=Pp[1][3]-bp1*p33; P2[2][2]=Pp[2][2]-bp2*p32;
            P2[2][3]=Pp[2][3]-bp2*p33; P2[3][3]=Pp[3][3]-bp3*p33;

            // ---- IMM mixing ----
            const float e1 = __expf(ll1), e2 = __expf(ll2);
            const float num1 = e1 * (pr1 * p11);
            const float num2 = e2 * (pr1 * (1.0f - p11) + pr2);
            const float marg = num1 + num2 + 1e-9f;
            const float im   = frcp(marg);
            const float w1   = num1 * im;
            const float w2m  = num2 * im;
            llacc += __logf(marg);

            float etat[4], d1[4], d2v[4], wd1[4], wd2[4];
#pragma unroll
            for (int l = 0; l < 4; ++l) {
                etat[l] = w1*eta1[l] + w2m*eta2[l];
                d1[l]  = eta1[l] - etat[l];
                d2v[l] = eta2[l] - etat[l];
                wd1[l] = w1*d1[l];
                wd2[l] = w2m*d2v[l];
            }
#pragma unroll
            for (int i = 0; i < 4; ++i)
#pragma unroll
                for (int j = i; j < 4; ++j) {
                    const float val = w1*P1[i][j] + w2m*P2[i][j]
                                    + wd1[i]*d1[j] + wd2[i]*d2v[j];
                    P[i][j] = val; P[j][i] = val;
                }
#pragma unroll
            for (int l = 0; l < 4; ++l) eta[l] = etat[l];
            pr1 = w1; pr2 = w2m;

            // ---- outputs ----
            pb[0] = w1; pb[1] = w2m; pb += 2;
            const float we0 = w1*etat[0], we1 = w1*etat[1], we2 = w1*etat[2];
            const float weB = w2m*etat[3];
            yp[0] = lam1[0]*we0 + lam2[0]*weB;
            yp[1] = lam1[1]*we0 + lam2[1]*weB;
            yp[2] = lam1[2]*we0 + lam2[2]*weB;
            yp[3] = lam1[3]*we1 + lam2[3]*weB;
            yp[4] = lam1[4]*we1 + lam2[4]*weB;
            yp[5] = lam1[5]*we1 + lam2[5]*weB;
            yp[6] = lam1[6]*we2 + lam2[6]*weB;
            yp[7] = lam1[7]*we2 + lam2[7]*weB;
            yp[8] = lam1[8]*we2 + lam2[8]*weB;
            yp += N_O;
        }

#pragma unroll
        for (int o = 0; o < 9; ++o) ycur[o] = ynx[o];
    }

    // ---- wave reduction of ll, one atomic per block ----
#pragma unroll
    for (int off = 32; off > 0; off >>= 1)
        llacc += __shfl_down(llacc, off, 64);
    if (threadIdx.x == 0) atomicAdd(ll_ws, llacc);
}

__global__ void finalize_kernel(const float* __restrict__ ll_ws, float* __restrict__ out0)
{
    out0[0] = -ll_ws[0];
}

extern "C" void kernel_launch(void* const* d_in, const int* in_sizes, int n_in,
                              void* d_out, int out_size, void* d_ws, size_t ws_size,
                              hipStream_t stream)
{
    const float* y    = (const float*)d_in[0];
    const float* B1s1 = (const float*)d_in[1];
    const float* B1s2 = (const float*)d_in[2];
    const float* l1f  = (const float*)d_in[3];
    const float* l2f  = (const float*)d_in[4];
    const float* lq   = (const float*)d_in[5];
    const float* lr   = (const float*)d_in[6];
    const float* gi   = (const float*)d_in[7];
    const float* gc   = (const float*)d_in[8];

    float* out   = (float*)d_out;
    float* probs = out + 1;                                    // [N,NT,2]
    float* ypred = out + 1 + (size_t)N_PART * N_T * 2;         // [N,NT,9]
    float* ws    = (float*)d_ws;

    hipMemsetAsync(ws, 0, sizeof(float), stream);
    imm_kf_kernel<<<N_PART/64, 64, 0, stream>>>(y, B1s1, B1s2, l1f, l2f,
                                                lq, lr, gi, gc, probs, ypred, ws);
    finalize_kernel<<<1, 1, 0, stream>>>(ws, out);
}

// Round 4
// 570.056 us; speedup vs baseline: 1.8846x; 1.0068x over previous
//
#include <hip/hip_runtime.h>
#include <math.h>

#define N_PART 4096
#define N_T    400
#define N_O    9
#define LOG2PI_F 1.8378770664093453f

typedef float v2f __attribute__((ext_vector_type(2)));

__device__ __forceinline__ v2f v2exp(v2f x){ v2f r; r.x=__expf(x.x); r.y=__expf(x.y); return r; }
__device__ __forceinline__ v2f v2log(v2f x){ v2f r; r.x=__logf(x.x); r.y=__logf(x.y); return r; }
__device__ __forceinline__ v2f v2rcp(v2f x){ v2f r; r.x=__builtin_amdgcn_rcpf(x.x); r.y=__builtin_amdgcn_rcpf(x.y); return r; }

// Two particles per lane packed as float2 (<2 x float> -> v_pk_* where the
// backend can). 2048 threads = 32 waves. Main loop stores only a 6-float
// record [w1,w2,eta0..3] per (particle,t) into the ypred slot; expand_kernel
// rebuilds ypred(9)+probs(2) coalesced afterwards.
__global__ __launch_bounds__(64)
void imm_kf_kernel(const float* __restrict__ y,
                   const float* __restrict__ B1s1,
                   const float* __restrict__ B1s2,
                   const float* __restrict__ l1f,
                   const float* __restrict__ l2f,
                   const float* __restrict__ log_q,
                   const float* __restrict__ log_r,
                   const float* __restrict__ gip,
                   const float* __restrict__ gcp,
                   float* __restrict__ rec,        // ypred region, [N,NT,9] slots
                   float* __restrict__ ll_ws)
{
    const int n = blockIdx.x * 64 + threadIdx.x;   // pair index, 0..2047
    const int pA = 2*n, pB = 2*n + 1;

    // ---- uniform constants (scalar / SGPR) ----
    float B00=B1s1[0],B01=B1s1[1],B02=B1s1[2];
    float B10=B1s1[3],B11=B1s1[4],B12=B1s1[5];
    float B20=B1s1[6],B21=B1s1[7],B22=B1s1[8];
    const float b2 = B1s2[0];

    float lam1[9], lam2[9];
    lam1[0]=1.0f; lam1[1]=l1f[0]; lam1[2]=l1f[1];
    lam1[3]=1.0f; lam1[4]=l1f[2]; lam1[5]=l1f[3];
    lam1[6]=1.0f; lam1[7]=l1f[4]; lam1[8]=l1f[5];
    lam2[0]=1.0f;
#pragma unroll
    for (int o = 1; o < 9; ++o) lam2[o] = l2f[o-1];

    float q0=expf(log_q[0]), q1=expf(log_q[1]), q2=expf(log_q[2]), q3=expf(log_q[3]);

    float ri[9], aA[9], cB[9];
    float logdetR = 0.0f;
    float gA0=0.f, gA1=0.f, gA2=0.f, gB=0.f;
#pragma unroll
    for (int o = 0; o < 9; ++o) {
        const float rr  = expf(log_r[o]);
        const float rj  = rr + 1e-6f;          // R + JITTER folded
        const float riv = 1.0f / rj;
        ri[o] = riv;
        logdetR += logf(rj);
        aA[o] = lam1[o] * riv;
        cB[o] = lam2[o] * riv;
        const float ga = lam1[o]*aA[o];
        if (o < 3) gA0 += ga; else if (o < 6) gA1 += ga; else gA2 += ga;
        gB += lam2[o]*cB[o];
    }
    const float gi  = gip[0];
    const float gc0 = gcp[0], gc1 = gcp[1], gc2 = gcp[2];
    const float llconst = 9.0f * LOG2PI_F + logdetR;

    // ---- state (upper triangle of P, both particles packed) ----
    v2f P00={1000.f,1000.f}, P01={0,0}, P02={0,0}, P03={0,0};
    v2f P11={1000.f,1000.f}, P12={0,0}, P13={0,0};
    v2f P22={1000.f,1000.f}, P23={0,0};
    v2f P33={1000.f,1000.f};
    v2f e0={0,0}, e1={0,0}, e2={0,0}, e3={0,0};
    v2f pr1={0.99f,0.99f}, pr2={0.01f,0.01f};
    v2f llacc={0,0};

    const float* ybA = y + (size_t)pA * (N_T*N_O);
    const float* ybB = y + (size_t)pB * (N_T*N_O);
    float* wpA = rec + (size_t)pA * (N_T*N_O);
    float* wpB = rec + (size_t)pB * (N_T*N_O);

    v2f yc[9];
#pragma unroll
    for (int o = 0; o < 9; ++o) { yc[o].x = ybA[o]; yc[o].y = ybB[o]; }
    const float* ynpA = ybA + N_O;
    const float* ynpB = ybB + N_O;

    for (int t = 0; t < N_T; ++t) {
        // prefetch next timestep's observations
        v2f ynx[9];
#pragma unroll
        for (int o = 0; o < 9; ++o) { ynx[o].x = ynpA[o]; ynx[o].y = ynpB[o]; }
        if (t < N_T - 2) { ynpA += N_O; ynpB += N_O; }

        const v2f xg  = gi + e0*gc0 + e1*gc1 + e2*gc2;
        const v2f p11 = v2rcp(1.0f + v2exp(-xg));

        // ---- prediction: ep = B eta ; Pp = B P B^T + Q ----
        const v2f ep0 = B00*e0 + B01*e1 + B02*e2;
        const v2f ep1 = B10*e0 + B11*e1 + B12*e2;
        const v2f ep2 = B20*e0 + B21*e1 + B22*e2;
        const v2f ep3 = b2*e3;

        const v2f C00 = B00*P00 + B01*P01 + B02*P02;
        const v2f C01 = B00*P01 + B01*P11 + B02*P12;
        const v2f C02 = B00*P02 + B01*P12 + B02*P22;
        const v2f C10 = B10*P00 + B11*P01 + B12*P02;
        const v2f C11 = B10*P01 + B11*P11 + B12*P12;
        const v2f C12 = B10*P02 + B11*P12 + B12*P22;
        const v2f C20 = B20*P00 + B21*P01 + B22*P02;
        const v2f C21 = B20*P01 + B21*P11 + B22*P12;
        const v2f C22 = B20*P02 + B21*P12 + B22*P22;

        const v2f Pp00 = C00*B00 + C01*B01 + C02*B02 + q0;
        const v2f Pp01 = C00*B10 + C01*B11 + C02*B12;
        const v2f Pp02 = C00*B20 + C01*B21 + C02*B22;
        const v2f Pp11 = C10*B10 + C11*B11 + C12*B12 + q1;
        const v2f Pp12 = C10*B20 + C11*B21 + C12*B22;
        const v2f Pp22 = C20*B20 + C21*B21 + C22*B22 + q2;
        const v2f Pp03 = b2*(B00*P03 + B01*P13 + B02*P23);
        const v2f Pp13 = b2*(B10*P03 + B11*P13 + B12*P23);
        const v2f Pp23 = b2*(B20*P03 + B21*P13 + B22*P23);
        const v2f Pp33 = b2*b2*P33 + q3;

        // ---- regime 1 (Woodbury, diagonal G, simple covariance form) ----
        v2f v1[9];
        v1[0]=yc[0]-lam1[0]*ep0; v1[1]=yc[1]-lam1[1]*ep0; v1[2]=yc[2]-lam1[2]*ep0;
        v1[3]=yc[3]-lam1[3]*ep1; v1[4]=yc[4]-lam1[4]*ep1; v1[5]=yc[5]-lam1[5]*ep1;
        v1[6]=yc[6]-lam1[6]*ep2; v1[7]=yc[7]-lam1[7]*ep2; v1[8]=yc[8]-lam1[8]*ep2;
        v2f vRv1 = {0,0};
#pragma unroll
        for (int o = 0; o < 9; ++o) vRv1 += v1[o]*v1[o]*ri[o];
        const v2f b0  = aA[0]*v1[0] + aA[1]*v1[1] + aA[2]*v1[2];
        const v2f b1  = aA[3]*v1[3] + aA[4]*v1[4] + aA[5]*v1[5];
        const v2f bb2 = aA[6]*v1[6] + aA[7]*v1[7] + aA[8]*v1[8];

        const v2f A00 = 1.0f + gA0*Pp00, A01 = gA0*Pp01, A02 = gA0*Pp02;
        const v2f A10 = gA1*Pp01, A11 = 1.0f + gA1*Pp11, A12 = gA1*Pp12;
        const v2f A20 = gA2*Pp02, A21 = gA2*Pp12, A22 = 1.0f + gA2*Pp22;

        const v2f c00 = A11*A22 - A12*A21;
        const v2f c01 = A12*A20 - A10*A22;
        const v2f c02 = A10*A21 - A11*A20;
        const v2f det = A00*c00 + A01*c01 + A02*c02;   // det(I+GS) > 1
        const v2f idet = v2rcp(det);
        const v2f Ai00 = c00*idet;
        const v2f Ai01 = (A02*A21 - A01*A22)*idet;
        const v2f Ai02 = (A01*A12 - A02*A11)*idet;
        const v2f Ai10 = c01*idet;
        const v2f Ai11 = (A00*A22 - A02*A20)*idet;
        const v2f Ai12 = (A02*A10 - A00*A12)*idet;
        const v2f Ai20 = c02*idet;
        const v2f Ai21 = (A01*A20 - A00*A21)*idet;
        const v2f Ai22 = (A00*A11 - A01*A10)*idet;

        const v2f u0 = Ai00*b0 + Ai01*b1 + Ai02*bb2;
        const v2f u1 = Ai10*b0 + Ai11*b1 + Ai12*bb2;
        const v2f uu2= Ai20*b0 + Ai21*b1 + Ai22*bb2;
        const v2f sb0 = Pp00*b0 + Pp01*b1 + Pp02*bb2;
        const v2f sb1 = Pp01*b0 + Pp11*b1 + Pp12*bb2;
        const v2f sb2 = Pp02*b0 + Pp12*b1 + Pp22*bb2;
        const v2f qf1 = vRv1 - (u0*sb0 + u1*sb1 + uu2*sb2);
        const v2f ll1 = -0.5f*(llconst + v2log(det) + qf1);

        // W = Ainv*G (symmetric)
        const v2f W00 = Ai00*gA0, W01 = Ai01*gA1, W02 = Ai02*gA2;
        const v2f W11 = Ai11*gA1, W12 = Ai12*gA2, W22 = Ai22*gA2;

        // Pc rows
        const v2f r00=Pp00, r01=Pp01, r02=Pp02;
        const v2f r10=Pp01, r11=Pp11, r12=Pp12;
        const v2f r20=Pp02, r21=Pp12, r22=Pp22;
        const v2f r30=Pp03, r31=Pp13, r32=Pp23;

        const v2f eta1_0 = ep0 + r00*u0 + r01*u1 + r02*uu2;
        const v2f eta1_1 = ep1 + r10*u0 + r11*u1 + r12*uu2;
        const v2f eta1_2 = ep2 + r20*u0 + r21*u1 + r22*uu2;
        const v2f eta1_3 = ep3 + r30*u0 + r31*u1 + r32*uu2;

        const v2f Jg00=r00*W00+r01*W01+r02*W02, Jg01=r00*W01+r01*W11+r02*W12, Jg02=r00*W02+r01*W12+r02*W22;
        const v2f Jg10=r10*W00+r11*W01+r12*W02, Jg11=r10*W01+r11*W11+r12*W12, Jg12=r10*W02+r11*W12+r12*W22;
        const v2f Jg20=r20*W00+r21*W01+r22*W02, Jg21=r20*W01+r21*W11+r22*W12, Jg22=r20*W02+r21*W12+r22*W22;
        const v2f Jg30=r30*W00+r31*W01+r32*W02, Jg31=r30*W01+r31*W11+r32*W12, Jg32=r30*W02+r31*W12+r32*W22;

        const v2f P1_00 = Pp00 - (Jg00*r00 + Jg01*r01 + Jg02*r02);
        const v2f P1_01 = Pp01 - (Jg00*r10 + Jg01*r11 + Jg02*r12);
        const v2f P1_02 = Pp02 - (Jg00*r20 + Jg01*r21 + Jg02*r22);
        const v2f P1_03 = Pp03 - (Jg00*r30 + Jg01*r31 + Jg02*r32);
        const v2f P1_11 = Pp11 - (Jg10*r10 + Jg11*r11 + Jg12*r12);
        const v2f P1_12 = Pp12 - (Jg10*r20 + Jg11*r21 + Jg12*r22);
        const v2f P1_13 = Pp13 - (Jg10*r30 + Jg11*r31 + Jg12*r32);
        const v2f P1_22 = Pp22 - (Jg20*r20 + Jg21*r21 + Jg22*r22);
        const v2f P1_23 = Pp23 - (Jg20*r30 + Jg21*r31 + Jg22*r32);
        const v2f P1_33 = Pp33 - (Jg30*r30 + Jg31*r31 + Jg32*r32);

        // ---- regime 2 (rank-1 Sherman-Morrison) ----
        v2f vRv2 = {0,0}, bv2 = {0,0};
#pragma unroll
        for (int o = 0; o < 9; ++o) {
            const v2f v2o = yc[o] - lam2[o]*ep3;
            vRv2 += v2o*v2o*ri[o];
            bv2  += cB[o]*v2o;
        }
        const v2f s22 = Pp33;
        const v2f d2  = 1.0f + s22*gB;
        const v2f id2 = v2rcp(d2);
        const v2f qf2 = vRv2 - s22*id2*bv2*bv2;
        const v2f ll2 = -0.5f*(llconst + v2log(d2) + qf2);
        const v2f kv  = bv2*id2;
        const v2f eta2_0 = ep0 + Pp03*kv;
        const v2f eta2_1 = ep1 + Pp13*kv;
        const v2f eta2_2 = ep2 + Pp23*kv;
        const v2f eta2_3 = ep3 + Pp33*kv;
        const v2f beta = gB*id2;
        const v2f bp0 = beta*Pp03, bp1 = beta*Pp13, bp2 = beta*Pp23, bp3 = beta*Pp33;
        const v2f P2_00 = Pp00 - bp0*Pp03;
        const v2f P2_01 = Pp01 - bp0*Pp13;
        const v2f P2_02 = Pp02 - bp0*Pp23;
        const v2f P2_03 = Pp03 - bp0*Pp33;
        const v2f P2_11 = Pp11 - bp1*Pp13;
        const v2f P2_12 = Pp12 - bp1*Pp23;
        const v2f P2_13 = Pp13 - bp1*Pp33;
        const v2f P2_22 = Pp22 - bp2*Pp23;
        const v2f P2_23 = Pp23 - bp2*Pp33;
        const v2f P2_33 = Pp33 - bp3*Pp33;

        // ---- IMM mixing ----
        const v2f ex1 = v2exp(ll1), ex2 = v2exp(ll2);
        const v2f num1 = ex1 * (pr1 * p11);
        const v2f num2 = ex2 * (pr1 * (1.0f - p11) + pr2);
        const v2f marg = num1 + num2 + 1e-9f;
        const v2f im   = v2rcp(marg);
        const v2f w1   = num1 * im;
        const v2f w2m  = num2 * im;
        llacc += v2log(marg);

        const v2f et0 = w1*eta1_0 + w2m*eta2_0;
        const v2f et1 = w1*eta1_1 + w2m*eta2_1;
        const v2f et2 = w1*eta1_2 + w2m*eta2_2;
        const v2f et3 = w1*eta1_3 + w2m*eta2_3;
        const v2f d1_0 = eta1_0-et0, d1_1 = eta1_1-et1, d1_2 = eta1_2-et2, d1_3 = eta1_3-et3;
        const v2f d2_0 = eta2_0-et0, d2_1 = eta2_1-et1, d2_2 = eta2_2-et2, d2_3 = eta2_3-et3;
        const v2f wd1_0=w1*d1_0, wd1_1=w1*d1_1, wd1_2=w1*d1_2, wd1_3=w1*d1_3;
        const v2f wd2_0=w2m*d2_0, wd2_1=w2m*d2_1, wd2_2=w2m*d2_2, wd2_3=w2m*d2_3;

        P00 = w1*P1_00 + w2m*P2_00 + wd1_0*d1_0 + wd2_0*d2_0;
        P01 = w1*P1_01 + w2m*P2_01 + wd1_0*d1_1 + wd2_0*d2_1;
        P02 = w1*P1_02 + w2m*P2_02 + wd1_0*d1_2 + wd2_0*d2_2;
        P03 = w1*P1_03 + w2m*P2_03 + wd1_0*d1_3 + wd2_0*d2_3;
        P11 = w1*P1_11 + w2m*P2_11 + wd1_1*d1_1 + wd2_1*d2_1;
        P12 = w1*P1_12 + w2m*P2_12 + wd1_1*d1_2 + wd2_1*d2_2;
        P13 = w1*P1_13 + w2m*P2_13 + wd1_1*d1_3 + wd2_1*d2_3;
        P22 = w1*P1_22 + w2m*P2_22 + wd1_2*d1_2 + wd2_2*d2_2;
        P23 = w1*P1_23 + w2m*P2_23 + wd1_2*d1_3 + wd2_2*d2_3;
        P33 = w1*P1_33 + w2m*P2_33 + wd1_3*d1_3 + wd2_3*d2_3;

        e0 = et0; e1 = et1; e2 = et2; e3 = et3;
        pr1 = w1; pr2 = w2m;

        // ---- store 6-float record into the ypred slot ----
        wpA[0]=w1.x;  wpA[1]=w2m.x; wpA[2]=et0.x; wpA[3]=et1.x; wpA[4]=et2.x; wpA[5]=et3.x;
        wpB[0]=w1.y;  wpB[1]=w2m.y; wpB[2]=et0.y; wpB[3]=et1.y; wpB[4]=et2.y; wpB[5]=et3.y;
        wpA += N_O; wpB += N_O;

#pragma unroll
        for (int o = 0; o < 9; ++o) yc[o] = ynx[o];
    }

    // ---- wave reduction of ll, one atomic per block ----
    float lls = llacc.x + llacc.y;
#pragma unroll
    for (int off = 32; off > 0; off >>= 1)
        lls += __shfl_down(lls, off, 64);
    if (threadIdx.x == 0) atomicAdd(ll_ws, lls);
}

// Expand [w1,w2,e0..e3] records in-place into ypred(9) and probs(2), coalesced.
// 64 slots (= 576 ypred floats, 128 probs floats) per block.
__global__ __launch_bounds__(64)
void expand_kernel(const float* __restrict__ l1f, const float* __restrict__ l2f,
                   float* __restrict__ ypred, float* __restrict__ probs)
{
    __shared__ float buf[576];
    __shared__ float pbuf[128];
    const int tid = threadIdx.x;
    float* gp = ypred + (size_t)blockIdx.x * 576;
#pragma unroll
    for (int k = 0; k < 9; ++k) buf[tid + 64*k] = gp[tid + 64*k];

    float lam1[9], lam2[9];
    lam1[0]=1.0f; lam1[1]=l1f[0]; lam1[2]=l1f[1];
    lam1[3]=1.0f; lam1[4]=l1f[2]; lam1[5]=l1f[3];
    lam1[6]=1.0f; lam1[7]=l1f[4]; lam1[8]=l1f[5];
    lam2[0]=1.0f;
#pragma unroll
    for (int o = 1; o < 9; ++o) lam2[o] = l2f[o-1];

    __syncthreads();
    float* r = buf + tid*9;                 // stride 9: conflict-free
    const float w1=r[0], w2=r[1], e0=r[2], e1=r[3], e2=r[4], e3=r[5];
    const float we0=w1*e0, we1=w1*e1, we2=w1*e2, weB=w2*e3;
    r[0]=lam1[0]*we0+lam2[0]*weB;
    r[1]=lam1[1]*we0+lam2[1]*weB;
    r[2]=lam1[2]*we0+lam2[2]*weB;
    r[3]=lam1[3]*we1+lam2[3]*weB;
    r[4]=lam1[4]*we1+lam2[4]*weB;
    r[5]=lam1[5]*we1+lam2[5]*weB;
    r[6]=lam1[6]*we2+lam2[6]*weB;
    r[7]=lam1[7]*we2+lam2[7]*weB;
    r[8]=lam1[8]*we2+lam2[8]*weB;
    pbuf[tid*2]   = w1;
    pbuf[tid*2+1] = w2;
    __syncthreads();
#pragma unroll
    for (int k = 0; k < 9; ++k) gp[tid + 64*k] = buf[tid + 64*k];
    float* pp = probs + (size_t)blockIdx.x * 128;
    pp[tid]      = pbuf[tid];
    pp[tid + 64] = pbuf[tid + 64];
}

__global__ void finalize_kernel(const float* __restrict__ ll_ws, float* __restrict__ out0)
{
    out0[0] = -ll_ws[0];
}

extern "C" void kernel_launch(void* const* d_in, const int* in_sizes, int n_in,
                              void* d_out, int out_size, void* d_ws, size_t ws_size,
                              hipStream_t stream)
{
    const float* y    = (const float*)d_in[0];
    const float* B1s1 = (const float*)d_in[1];
    const float* B1s2 = (const float*)d_in[2];
    const float* l1f  = (const float*)d_in[3];
    const float* l2f  = (const float*)d_in[4];
    const float* lq   = (const float*)d_in[5];
    const float* lr   = (const float*)d_in[6];
    const float* gi   = (const float*)d_in[7];
    const float* gc   = (const float*)d_in[8];

    float* out   = (float*)d_out;
    float* probs = out + 1;                                    // [N,NT,2]
    float* ypred = out + 1 + (size_t)N_PART * N_T * 2;         // [N,NT,9]
    float* ws    = (float*)d_ws;

    hipMemsetAsync(ws, 0, sizeof(float), stream);
    imm_kf_kernel<<<(N_PART/2)/64, 64, 0, stream>>>(y, B1s1, B1s2, l1f, l2f,
                                                    lq, lr, gi, gc, ypred, ws);
    expand_kernel<<<(N_PART*N_T)/64, 64, 0, stream>>>(l1f, l2f, ypred, probs);
    finalize_kernel<<<1, 1, 0, stream>>>(ws, out);
}